// Round 8
// baseline (361.152 us; speedup 1.0000x reference)
//
#include <hip/hip_runtime.h>
#include <hip/hip_bf16.h>
#include <float.h>
#include <math.h>

#define Bz 8
#define Dd 256
#define Tt 2048
#define Kk 8192
#define Mm (Bz*Tt)          // 16384 rows (b*T + t)

// Scorer v15 (unchanged, proven 112us): 128x256, 8 waves, swapped-operand
// epilogue. This round attacks the non-mfma 181us: k_combine slimmed (no
// pair emission, 256 blocks x 64 thr), new wave-per-row k_rescan_rows
// (lanes scan splits + process candidates in parallel; no pair list, no
// PAIR_CAP), k_rescan_final folded into k_out via posm[], k_gather sumsq
// parallelized over 8 lanes.
#define NSPL 32

#define ZG_CAP 4096

// Margin: covers f16 fast-pass score error + np fp32 quantization straddle
#define RESCAN_MARGIN 6e-4f

typedef __attribute__((ext_vector_type(8))) _Float16 f16x8;
typedef __attribute__((ext_vector_type(4))) float    f32x4;

// async global->LDS DMA, 16 B per lane; lds dest = wave-uniform base + lane*16
__device__ __forceinline__ void gld16(const void* g, void* l) {
  __builtin_amdgcn_global_load_lds(
      (const __attribute__((address_space(1))) void*)g,
      (__attribute__((address_space(3))) void*)l, 16, 0, 0);
}

// ---------------------------------------------------------------------------
// numpy-faithful pairwise sum of squares (blocksize-128 pairwise, 8 accums)
// ---------------------------------------------------------------------------
__device__ __forceinline__ float np_sumsq128(const float* __restrict__ x) {
  float r0 = __fmul_rn(x[0], x[0]);
  float r1 = __fmul_rn(x[1], x[1]);
  float r2 = __fmul_rn(x[2], x[2]);
  float r3 = __fmul_rn(x[3], x[3]);
  float r4 = __fmul_rn(x[4], x[4]);
  float r5 = __fmul_rn(x[5], x[5]);
  float r6 = __fmul_rn(x[6], x[6]);
  float r7 = __fmul_rn(x[7], x[7]);
  for (int i = 8; i < 128; i += 8) {
    r0 = __fadd_rn(r0, __fmul_rn(x[i+0], x[i+0]));
    r1 = __fadd_rn(r1, __fmul_rn(x[i+1], x[i+1]));
    r2 = __fadd_rn(r2, __fmul_rn(x[i+2], x[i+2]));
    r3 = __fadd_rn(r3, __fmul_rn(x[i+3], x[i+3]));
    r4 = __fadd_rn(r4, __fmul_rn(x[i+4], x[i+4]));
    r5 = __fadd_rn(r5, __fmul_rn(x[i+5], x[i+5]));
    r6 = __fadd_rn(r6, __fmul_rn(x[i+6], x[i+6]));
    r7 = __fadd_rn(r7, __fmul_rn(x[i+7], x[i+7]));
  }
  return __fadd_rn(__fadd_rn(__fadd_rn(r0, r1), __fadd_rn(r2, r3)),
                   __fadd_rn(__fadd_rn(r4, r5), __fadd_rn(r6, r7)));
}
__device__ __forceinline__ float np_sumsq256(const float* __restrict__ x) {
  return __fadd_rn(np_sumsq128(x), np_sumsq128(x + 128));
}

// ---------------------------------------------------------------------------
// k_pre: fused [cast_z | cast_cb | prep] by blockIdx range (fewer launches)
// ---------------------------------------------------------------------------
__global__ void k_pre(const float* __restrict__ z, const float* __restrict__ cb,
                      _Float16* __restrict__ Ah, _Float16* __restrict__ Bh,
                      float* __restrict__ sc,
                      double* __restrict__ loss_accum, int* __restrict__ rc) {
  const int bid = blockIdx.x;
  const int tid = threadIdx.x;
  if (bid < 1024) {
    // ---- transpose-cast z (B,D,T) f32 -> Ah (M,D) f16
    __shared__ _Float16 tile[64][64 + 8];
    const int b  = bid >> 7;
    const int dt = (bid >> 5) & 3;
    const int tt = bid & 31;
    const int d0 = dt * 64, t0 = tt * 64;
    const float* zb = z + ((size_t)b * Dd + d0) * Tt + t0;
    #pragma unroll
    for (int p = 0; p < 4; ++p) {
      const int d  = p * 16 + (tid >> 4);
      const int tl = (tid & 15) * 4;
      const float4 v = *(const float4*)(zb + (size_t)d * Tt + tl);
      tile[tl+0][d] = (_Float16)v.x;
      tile[tl+1][d] = (_Float16)v.y;
      tile[tl+2][d] = (_Float16)v.z;
      tile[tl+3][d] = (_Float16)v.w;
    }
    __syncthreads();
    const int r = tid >> 2, seg = tid & 3;
    const int m = b * Tt + t0 + r;
    int4* dst = (int4*)(Ah + (size_t)m * Dd + d0 + seg * 16);
    const int4* srcv = (const int4*)(&tile[r][seg * 16]);
    dst[0] = srcv[0];
    dst[1] = srcv[1];
  } else if (bid < 2048) {
    // ---- cast codebook f32 -> f16, prescaled by 256
    const size_t g = (size_t)(bid - 1024) * 256 + tid;
    const float4 v0 = *(const float4*)(cb + g * 8);
    const float4 v1 = *(const float4*)(cb + g * 8 + 4);
    f16x8 o;
    o[0] = (_Float16)(v0.x * 256.f); o[1] = (_Float16)(v0.y * 256.f);
    o[2] = (_Float16)(v0.z * 256.f); o[3] = (_Float16)(v0.w * 256.f);
    o[4] = (_Float16)(v1.x * 256.f); o[5] = (_Float16)(v1.y * 256.f);
    o[6] = (_Float16)(v1.z * 256.f); o[7] = (_Float16)(v1.w * 256.f);
    *(f16x8*)(Bh + g * 8) = o;
  } else {
    // ---- np-faithful codebook norms (8 lanes own np's 8 acc chains)
    if (bid == 2048 && tid == 0) {
      *loss_accum = 0.0; rc[0] = 0; rc[1] = 0; rc[2] = 0;
    }
    const int gid = (bid - 2048) * 256 + tid;
    const int lane = gid & 63;
    const int j = lane & 7, sub = lane >> 3;
    const int row = (gid >> 6) * 8 + sub;
    if (row >= Kk) return;
    const float* x = cb + (size_t)row * Dd;
    float c0 = __fmul_rn(x[j], x[j]);
    float c1 = __fmul_rn(x[128 + j], x[128 + j]);
    #pragma unroll
    for (int i = 8; i < 128; i += 8) {
      c0 = __fadd_rn(c0, __fmul_rn(x[j + i], x[j + i]));
      c1 = __fadd_rn(c1, __fmul_rn(x[128 + j + i], x[128 + j + i]));
    }
    #pragma unroll
    for (int off = 1; off <= 4; off <<= 1) {
      c0 = __fadd_rn(c0, __shfl_xor(c0, off));
      c1 = __fadd_rn(c1, __shfl_xor(c1, off));
    }
    if (j == 0) sc[row] = __fadd_rn(c0, c1);
  }
}

// ---------------------------------------------------------------------------
// f16 MFMA score pass v15 (128x256, 8 waves, swapped-operand epilogue)
// ---------------------------------------------------------------------------
__global__ __launch_bounds__(512, 4)
void k_mfma(const _Float16* __restrict__ Ah, const _Float16* __restrict__ Bh,
            const float* __restrict__ sc,
            float* __restrict__ pd1, float* __restrict__ pd2, int* __restrict__ pi1) {
  __shared__ __align__(16) _Float16 As[128 * 64];   // 16 KB, dense 128 B rows
  __shared__ __align__(16) _Float16 Bs[256 * 64];   // 32 KB
  __shared__ float mr1[512];
  __shared__ float mr2[512];
  __shared__ int   mri[512];

  const int tid  = threadIdx.x;
  const int bx   = blockIdx.x & 31;      // 32 n-tiles of 256 cols (natural order)
  const int by   = blockIdx.x >> 5;      // 128 m-tiles of 128 rows
  const int m0   = by * 128, n0 = bx * 256;
  const int w    = tid >> 6, lane = tid & 63;
  const int wy   = w >> 2, wx = w & 3;   // 2 row-bands x 4 col-quarters
  const int l15  = lane & 15, quad = lane >> 4;
  const int lhi  = lane >> 3, llo = lane & 7;   // staging roles
  const int p    = llo ^ lhi;                   // swizzled source granule
  const int sw   = l15 & 7;                     // read-side swizzle key

  f32x4 acc[4][4];
  #pragma unroll
  for (int mi = 0; mi < 4; ++mi)
    #pragma unroll
    for (int ni = 0; ni < 4; ++ni)
      acc[mi][ni] = (f32x4){0.f, 0.f, 0.f, 0.f};

  // ---- K loop: per kc stage A (128x64) + B (256x64), then 2 ks x 16 MFMA
  for (int kc = 0; kc < 4; ++kc) {
    __syncthreads();                           // prior LDS reads done
    #pragma unroll
    for (int i = 0; i < 2; ++i) {              // A: 16 chunks of 8 rows x 128 B
      const int c  = w * 2 + i;
      const int r8 = c * 8 + lhi;
      gld16(Ah + (size_t)(m0 + r8) * Dd + kc * 64 + p * 8, As + c * 512);
    }
    #pragma unroll
    for (int i = 0; i < 4; ++i) {              // B: 32 chunks
      const int c  = w * 4 + i;
      const int r8 = c * 8 + lhi;
      gld16(Bh + (size_t)(n0 + r8) * Dd + kc * 64 + p * 8, Bs + c * 512);
    }
    __syncthreads();                           // drains vmcnt -> data visible
    #pragma unroll
    for (int ks = 0; ks < 2; ++ks) {
      f16x8 af[4], bf[4];
      #pragma unroll
      for (int mi = 0; mi < 4; ++mi)
        af[mi] = *(const f16x8*)(As + (wy*64 + mi*16 + l15) * 64 + (((ks*4 + quad) ^ sw) * 8));
      #pragma unroll
      for (int ni = 0; ni < 4; ++ni)
        bf[ni] = *(const f16x8*)(Bs + (wx*64 + ni*16 + l15) * 64 + (((ks*4 + quad) ^ sw) * 8));
      // SWAPPED operands: D[code][zrow]; same dot, same chain -> bit-identical
      #pragma unroll
      for (int mi = 0; mi < 4; ++mi)
        #pragma unroll
        for (int ni = 0; ni < 4; ++ni)
          acc[mi][ni] = __builtin_amdgcn_mfma_f32_16x16x32_f16(bf[ni], af[mi], acc[mi][ni], 0, 0, 0);
    }
  }

  // ---- epilogue: lane = z-row (l15); codes in-register (ni*16 + quad*4 + r)
  float scv[4][4];
  #pragma unroll
  for (int ni = 0; ni < 4; ++ni)
    *(float4*)&scv[ni][0] = *(const float4*)(sc + n0 + wx * 64 + ni * 16 + quad * 4);

  float s1[4], s2[4]; int i1[4];
  #pragma unroll
  for (int mi = 0; mi < 4; ++mi) {
    float a1 = INFINITY, a2 = INFINITY; int ai = 0x7fffffff;
    #pragma unroll
    for (int ni = 0; ni < 4; ++ni)
      #pragma unroll
      for (int r = 0; r < 4; ++r) {            // (ni,r) ascending -> k ascending
        const float sv = fmaf(-0.0078125f, acc[mi][ni][r], scv[ni][r]);  // -2/256
        const int   k  = n0 + wx * 64 + ni * 16 + quad * 4 + r;
        if (sv < a1) { a2 = a1; a1 = sv; ai = k; }
        else if (sv < a2) a2 = sv;
      }
    s1[mi] = a1; s2[mi] = a2; i1[mi] = ai;
  }

  // fold across the 4 quad-groups (codes quad*4+r) -- 2 shuffle steps x 4 q
  #pragma unroll
  for (int off = 16; off <= 32; off <<= 1)
    #pragma unroll
    for (int q = 0; q < 4; ++q) {
      const float o1 = __shfl_xor(s1[q], off);
      const float o2 = __shfl_xor(s2[q], off);
      const int   oi = __shfl_xor(i1[q], off);
      const float n2 = fminf(fminf(s2[q], o2), fmaxf(s1[q], o1));
      if (o1 < s1[q] || (o1 == s1[q] && oi < i1[q])) { s1[q] = o1; i1[q] = oi; }
      s2[q] = n2;
    }

  // merge the 4 wx col-quarters via LDS
  if (quad == 0) {
    #pragma unroll
    for (int mi = 0; mi < 4; ++mi) {
      const int ml = wy * 64 + mi * 16 + l15;  // 0..127
      mr1[ml * 4 + wx] = s1[mi];
      mr2[ml * 4 + wx] = s2[mi];
      mri[ml * 4 + wx] = i1[mi];
    }
  }
  __syncthreads();
  if (tid < 128) {
    float a1 = INFINITY, a2 = INFINITY; int ai = 0x7fffffff;
    #pragma unroll
    for (int x = 0; x < 4; ++x) {              // wx ascending -> k ascending
      const float b1 = mr1[tid * 4 + x], b2 = mr2[tid * 4 + x];
      const int   bi = mri[tid * 4 + x];
      if (b1 < a1 || (b1 == a1 && bi < ai)) { a2 = fminf(a1, b2); a1 = b1; ai = bi; }
      else a2 = fminf(a2, b1);
    }
    const size_t o = (size_t)bx * Mm + (size_t)(m0 + tid);  // split = 256-col window
    pd1[o] = a1; pd2[o] = a2; pi1[o] = ai;
  }
}

// ---------------------------------------------------------------------------
// combine the NSPL partials per row; flag near-ties (slim: no pair emission)
// ---------------------------------------------------------------------------
__global__ void k_combine(const float* __restrict__ pd1, const float* __restrict__ pd2,
                          const int* __restrict__ pi1, int* __restrict__ idxf,
                          int* __restrict__ rc, int* __restrict__ rlist,
                          float* __restrict__ rthr, int* __restrict__ posm,
                          int* __restrict__ slist, float* __restrict__ outIdx) {
  const int m = blockIdx.x * 64 + threadIdx.x;
  if (m >= Mm) return;
  float a1 = INFINITY, a2 = INFINITY; int ai = 0x7fffffff;
  #pragma unroll
  for (int spl = 0; spl < NSPL; ++spl) {         // spl ascending -> k ascending
    const size_t o = (size_t)spl * Mm + m;
    const float b1 = pd1[o], b2 = pd2[o]; const int bi = pi1[o];
    if (b1 < a1 || (b1 == a1 && bi < ai)) { a2 = fminf(a1, b2); a1 = b1; ai = bi; }
    else a2 = fminf(a2, b1);
  }
  idxf[m]   = ai;
  outIdx[m] = (float)ai;
  int pos = -1;
  if (a2 - a1 <= RESCAN_MARGIN) {
    const int p = atomicAdd(&rc[0], 1);
    if (p < ZG_CAP) {
      rlist[p] = m;
      rthr[p]  = a1 + RESCAN_MARGIN;
      pos = p;
    } else {
      // zg overflow: full slow scan for this row
      const int s = atomicAdd(&rc[2], 1); slist[s] = m;
    }
  }
  posm[m] = pos;
}

// ---------------------------------------------------------------------------
// gather flagged rows into compact zg; np norms (8-lane parallel, same tree
// as k_pre's norm branch); init packed minima
// ---------------------------------------------------------------------------
__global__ void k_gather(const float* __restrict__ z, const int* __restrict__ rc,
                         const int* __restrict__ rlist, float* __restrict__ zg,
                         float* __restrict__ Ag, unsigned long long* __restrict__ pbrow) {
  __shared__ float zr[Dd];
  const int cnt = min(rc[0], ZG_CAP);
  const int tid = threadIdx.x;
  for (int it = blockIdx.x; it < cnt; it += gridDim.x) {
    const int m = rlist[it];
    const int b = m / Tt, t = m & (Tt - 1);
    __syncthreads();
    zr[tid] = z[(size_t)b * Dd * Tt + (size_t)tid * Tt + t];
    __syncthreads();
    zg[(size_t)it * Dd + tid] = zr[tid];
    if (tid < 8) {
      const int j = tid;
      float c0 = __fmul_rn(zr[j], zr[j]);
      float c1 = __fmul_rn(zr[128 + j], zr[128 + j]);
      #pragma unroll
      for (int i = 8; i < 128; i += 8) {
        c0 = __fadd_rn(c0, __fmul_rn(zr[j + i], zr[j + i]));
        c1 = __fadd_rn(c1, __fmul_rn(zr[128 + j + i], zr[128 + j + i]));
      }
      #pragma unroll
      for (int off = 1; off <= 4; off <<= 1) {
        c0 = __fadd_rn(c0, __shfl_xor(c0, off));
        c1 = __fadd_rn(c1, __shfl_xor(c1, off));
      }
      if (j == 0) { Ag[it] = __fadd_rn(c0, c1); pbrow[it] = ~0ull; }
    }
  }
}

// ---------------------------------------------------------------------------
// exact rescan of one candidate: np-faithful fp64 dot (same segment grouping
// and rounding sequence as always), packed (orderable f32, idx) atomicMin.
// ---------------------------------------------------------------------------
__device__ __forceinline__ void rescan_cand(const float* __restrict__ cb,
                                            const float* __restrict__ sc,
                                            const float* __restrict__ zp,
                                            const float Az, const int k,
                                            unsigned long long* __restrict__ pb) {
  const float* __restrict__ cp = cb + (size_t)k * Dd;
  double M8 = 0.0;
  #pragma unroll
  for (int sg = 0; sg < 8; ++sg) {
    double a0 = 0.0, a1 = 0.0, a2 = 0.0, a3 = 0.0;
    #pragma unroll
    for (int j = 0; j < 32; j += 4) {
      const float4 c4 = *(const float4*)(cp + sg * 32 + j);
      const float4 z4 = *(const float4*)(zp + sg * 32 + j);
      a0 = fma((double)c4.x, (double)z4.x, a0);
      a1 = fma((double)c4.y, (double)z4.y, a1);
      a2 = fma((double)c4.z, (double)z4.z, a2);
      a3 = fma((double)c4.w, (double)z4.w, a3);
    }
    M8 += (a0 + a1) + (a2 + a3);
  }
  const float M  = (float)M8;
  const float t1 = __fsub_rn(Az, __fmul_rn(2.0f, M));
  const float dq = __fadd_rn(t1, sc[k]);
  unsigned int fb = __float_as_uint(dq);
  fb = (fb & 0x80000000u) ? ~fb : (fb | 0x80000000u);
  const unsigned long long pack = ((unsigned long long)fb << 32) | (unsigned)k;
  atomicMin(pb, pack);
}

// ---------------------------------------------------------------------------
// wave-per-row rescan: lanes 0..31 scan the splits; single-winner candidates
// are ballot-compacted and processed one per lane; dump-splits (pd2<=thr)
// are enumerated 64-wide. No pair list, no PAIR_CAP.
// ---------------------------------------------------------------------------
__global__ __launch_bounds__(256)
void k_rescan_rows(const float* __restrict__ cb, const float* __restrict__ sc,
                   const int* __restrict__ rc, const int* __restrict__ rlist,
                   const float* __restrict__ rthr,
                   const float* __restrict__ pd1, const float* __restrict__ pd2,
                   const int* __restrict__ pi1,
                   const float* __restrict__ zg, const float* __restrict__ Ag,
                   unsigned long long* __restrict__ pbrow) {
  __shared__ int clist[4][32];
  const int cnt  = min(rc[0], ZG_CAP);
  const int wv   = threadIdx.x >> 6;
  const int lane = threadIdx.x & 63;
  const int it   = blockIdx.x * 4 + wv;
  if (it >= cnt) return;
  const int   m   = rlist[it];
  const float thr = rthr[it];
  const float Az  = Ag[it];
  const float* __restrict__ zp = zg + (size_t)it * Dd;

  int  cand = -1;
  bool dump = false;
  if (lane < NSPL) {
    const size_t o = (size_t)lane * Mm + m;
    const float b1 = pd1[o], b2 = pd2[o];
    if (b2 <= thr) dump = true;
    else if (b1 <= thr) cand = pi1[o];
  }
  const unsigned long long m1 = __ballot(cand >= 0);
  unsigned long long m2 = __ballot(dump);
  if (cand >= 0)
    clist[wv][__popcll(m1 & ((1ull << lane) - 1))] = cand;
  asm volatile("s_waitcnt lgkmcnt(0)" ::: "memory");
  __builtin_amdgcn_sched_barrier(0);
  const int ns = __popcll(m1);
  if (lane < ns)
    rescan_cand(cb, sc, zp, Az, clist[wv][lane], pbrow + it);
  while (m2) {
    const int s = (int)(__ffsll((long long)m2) - 1); m2 &= m2 - 1;
    #pragma unroll
    for (int rr = 0; rr < 4; ++rr)
      rescan_cand(cb, sc, zp, Az, s * 256 + rr * 64 + lane, pbrow + it);
  }
}

// overflow fallback: normally 0 iterations
__global__ void k_rescan_slow(const float* __restrict__ z, const float* __restrict__ cb,
                              const float* __restrict__ sc,
                              const int* __restrict__ rc, const int* __restrict__ slist,
                              int* __restrict__ idxf, float* __restrict__ outIdx) {
  __shared__ float zrow[Dd];
  __shared__ float Ash;
  __shared__ float sval[256];
  __shared__ int   sidx[256];
  const int tid = threadIdx.x;
  const int cnt = rc[2];
  for (int it = blockIdx.x; it < cnt; it += gridDim.x) {
    const int m = slist[it];
    const int b = m / Tt, t = m & (Tt - 1);
    __syncthreads();
    zrow[tid] = z[(size_t)b * Dd * Tt + (size_t)tid * Tt + t];
    __syncthreads();
    if (tid == 0) Ash = np_sumsq256(zrow);
    __syncthreads();
    const float A = Ash;
    float best = INFINITY; int bi = 0x7fffffff;
    for (int k = tid; k < Kk; k += 256) {
      const float* cr = cb + (size_t)k * Dd;
      double a0 = 0.0, a1 = 0.0, a2 = 0.0, a3 = 0.0;
      for (int d = 0; d < Dd; d += 4) {
        const float4 c4 = *(const float4*)(cr + d);
        a0 = fma((double)c4.x, (double)zrow[d+0], a0);
        a1 = fma((double)c4.y, (double)zrow[d+1], a1);
        a2 = fma((double)c4.z, (double)zrow[d+2], a2);
        a3 = fma((double)c4.w, (double)zrow[d+3], a3);
      }
      const float M  = (float)((a0 + a1) + (a2 + a3));
      const float t1 = __fsub_rn(A, __fmul_rn(2.0f, M));
      const float dq = __fadd_rn(t1, sc[k]);
      if (dq < best) { best = dq; bi = k; }
    }
    sval[tid] = best; sidx[tid] = bi;
    __syncthreads();
    for (int off = 128; off; off >>= 1) {
      if (tid < off) {
        if (sval[tid+off] < sval[tid] ||
            (sval[tid+off] == sval[tid] && sidx[tid+off] < sidx[tid])) {
          sval[tid] = sval[tid+off]; sidx[tid] = sidx[tid+off];
        }
      }
      __syncthreads();
    }
    if (tid == 0) { idxf[m] = sidx[0]; outIdx[m] = (float)sidx[0]; }
    __syncthreads();
  }
}

// ---------------------------------------------------------------------------
// fused gather + transpose + STE + loss + final index resolution:
// out[b][d][t] = z + (cb[idx] - z); idx = pbrow result for rescanned rows.
// ---------------------------------------------------------------------------
__global__ void k_out(const float* __restrict__ z, const float* __restrict__ cb,
                      const int* __restrict__ idxf, const int* __restrict__ posm,
                      const unsigned long long* __restrict__ pbrow,
                      float* __restrict__ outZ, float* __restrict__ outIdx,
                      double* __restrict__ loss_accum) {
  __shared__ float tile[64][65];          // [d][t]
  const int tid = threadIdx.x;
  const int bidx = blockIdx.x;            // 8 * 4 * 32 = 1024
  const int b  = bidx >> 7;
  const int dt = (bidx >> 5) & 3;
  const int tt = bidx & 31;
  const int d0 = dt * 64, t0 = tt * 64;
  {
    const int r = tid >> 2, seg = tid & 3;
    const int m = b * Tt + t0 + r;
    int idx = idxf[m];
    const int pos = posm[m];
    if (pos >= 0) {
      const unsigned long long pb = pbrow[pos];
      if (pb != ~0ull) {
        idx = (int)(unsigned)(pb & 0xFFFFFFFFull);
        if (seg == 0) outIdx[m] = (float)idx;
      }
    }
    const float* src = cb + (size_t)idx * Dd + d0 + seg * 16;
    #pragma unroll
    for (int q4 = 0; q4 < 4; ++q4) {
      const float4 v = *(const float4*)(src + q4 * 4);
      tile[seg * 16 + q4 * 4 + 0][r] = v.x;
      tile[seg * 16 + q4 * 4 + 1][r] = v.y;
      tile[seg * 16 + q4 * 4 + 2][r] = v.z;
      tile[seg * 16 + q4 * 4 + 3][r] = v.w;
    }
  }
  __syncthreads();
  const float* zbase = z + ((size_t)b * Dd + d0) * Tt + t0;
  float*       obase = outZ + ((size_t)b * Dd + d0) * Tt + t0;
  double ls = 0.0;
  #pragma unroll
  for (int p = 0; p < 4; ++p) {
    const int d  = p * 16 + (tid >> 4);
    const int t4 = (tid & 15) * 4;
    const float4 zv = *(const float4*)(zbase + (size_t)d * Tt + t4);
    const float q0 = tile[d][t4+0], q1 = tile[d][t4+1];
    const float q2 = tile[d][t4+2], q3 = tile[d][t4+3];
    const float r0 = q0 - zv.x, r1 = q1 - zv.y, r2 = q2 - zv.z, r3 = q3 - zv.w;
    float4 o;
    o.x = zv.x + r0; o.y = zv.y + r1; o.z = zv.z + r2; o.w = zv.w + r3;
    *(float4*)(obase + (size_t)d * Tt + t4) = o;
    ls += (double)r0*r0 + (double)r1*r1 + (double)r2*r2 + (double)r3*r3;
  }
  #pragma unroll
  for (int off = 32; off; off >>= 1) ls += __shfl_down(ls, off);
  if ((tid & 63) == 0) atomicAdd(loss_accum, ls);
}

__global__ void k_finalize(const double* __restrict__ loss_accum, float* __restrict__ outLoss) {
  const double mean = *loss_accum / (double)((size_t)Bz * Dd * Tt);
  *outLoss = (float)(mean + 0.1 * mean);
}

// ---------------------------------------------------------------------------
extern "C" void kernel_launch(void* const* d_in, const int* in_sizes, int n_in,
                              void* d_out, int out_size, void* d_ws, size_t ws_size,
                              hipStream_t stream) {
  (void)in_sizes; (void)n_in; (void)out_size; (void)ws_size;
  const float* z  = (const float*)d_in[0];   // (B, D, T) fp32
  const float* cb = (const float*)d_in[1];   // (K, D)    fp32

  float* outZ    = (float*)d_out;
  float* outIdx  = outZ + (size_t)Bz * Dd * Tt;
  float* outLoss = outIdx + Mm;

  char* w = (char*)d_ws;
  double*    loss_accum = (double*)w;    w += 16;
  int*       rc         = (int*)w;       w += 16;   // [0]=rows [2]=slow
  int*       rlist      = (int*)w;       w += sizeof(int)   * Mm;
  int*       slist      = (int*)w;       w += sizeof(int)   * Mm;
  int*       idxf       = (int*)w;       w += sizeof(int)   * Mm;
  int*       posm       = (int*)w;       w += sizeof(int)   * Mm;
  float*     sc         = (float*)w;     w += sizeof(float) * Kk;
  float*     rthr       = (float*)w;     w += sizeof(float) * ZG_CAP;
  _Float16*  Ah         = (_Float16*)w;  w += sizeof(_Float16) * (size_t)Mm * Dd;
  _Float16*  Bh         = (_Float16*)w;  w += sizeof(_Float16) * (size_t)Kk * Dd;
  float*     zg         = (float*)w;     w += sizeof(float) * (size_t)ZG_CAP * Dd;
  float*     Ag         = (float*)w;     w += sizeof(float) * ZG_CAP;
  unsigned long long* pbrow = (unsigned long long*)w; w += sizeof(unsigned long long) * ZG_CAP;
  float*     pd1        = (float*)w;     w += sizeof(float) * (size_t)NSPL * Mm;
  float*     pd2        = (float*)w;     w += sizeof(float) * (size_t)NSPL * Mm;
  int*       pi1        = (int*)w;       /* total ~25 MB */

  k_pre         <<<dim3(2304), 256, 0, stream>>>(z, cb, Ah, Bh, sc, loss_accum, rc);
  k_mfma        <<<dim3((Mm / 128) * (Kk / 256)), 512, 0, stream>>>(Ah, Bh, sc, pd1, pd2, pi1);
  k_combine     <<<dim3(Mm / 64), 64, 0, stream>>>(pd1, pd2, pi1, idxf, rc, rlist, rthr, posm, slist, outIdx);
  k_gather      <<<dim3(256), 256, 0, stream>>>(z, rc, rlist, zg, Ag, pbrow);
  k_rescan_rows <<<dim3(ZG_CAP / 4), 256, 0, stream>>>(cb, sc, rc, rlist, rthr, pd1, pd2, pi1, zg, Ag, pbrow);
  k_rescan_slow <<<dim3(64), 256, 0, stream>>>(z, cb, sc, rc, slist, idxf, outIdx);
  k_out         <<<dim3(1024), 256, 0, stream>>>(z, cb, idxf, posm, pbrow, outZ, outIdx, loss_accum);
  k_finalize    <<<dim3(1), 1, 0, stream>>>(loss_accum, outLoss);
}

// Round 11
// 285.196 us; speedup vs baseline: 1.2663x; 1.2663x over previous
//
#include <hip/hip_runtime.h>
#include <hip/hip_bf16.h>
#include <float.h>
#include <math.h>

#define Bz 8
#define Dd 256
#define Tt 2048
#define Kk 8192
#define Mm (Bz*Tt)          // 16384 rows (b*T + t)

// Scorer v15 (unchanged, proven ~113us). Rescan v17c: wave-per-row processes
// single-winner candidates directly per lane; dump-splits (pd2<=thr) pushed
// as (row,split) entries, processed by k_rescan_dumps one block per entry,
// one code per thread, 32-lane-half shuffle reduce (R7-proven idiom only:
// 64-bit shfl offsets 16..1), one atomicMin per half. No serial tails.
#define NSPL 32

#define ZG_CAP 4096
#define DUMP_CAP (ZG_CAP * NSPL)

// Margin: covers f16 fast-pass score error + np fp32 quantization straddle
#define RESCAN_MARGIN 6e-4f

typedef __attribute__((ext_vector_type(8))) _Float16 f16x8;
typedef __attribute__((ext_vector_type(4))) float    f32x4;

// async global->LDS DMA, 16 B per lane; lds dest = wave-uniform base + lane*16
__device__ __forceinline__ void gld16(const void* g, void* l) {
  __builtin_amdgcn_global_load_lds(
      (const __attribute__((address_space(1))) void*)g,
      (__attribute__((address_space(3))) void*)l, 16, 0, 0);
}

// ---------------------------------------------------------------------------
// numpy-faithful pairwise sum of squares (blocksize-128 pairwise, 8 accums)
// ---------------------------------------------------------------------------
__device__ __forceinline__ float np_sumsq128(const float* __restrict__ x) {
  float r0 = __fmul_rn(x[0], x[0]);
  float r1 = __fmul_rn(x[1], x[1]);
  float r2 = __fmul_rn(x[2], x[2]);
  float r3 = __fmul_rn(x[3], x[3]);
  float r4 = __fmul_rn(x[4], x[4]);
  float r5 = __fmul_rn(x[5], x[5]);
  float r6 = __fmul_rn(x[6], x[6]);
  float r7 = __fmul_rn(x[7], x[7]);
  for (int i = 8; i < 128; i += 8) {
    r0 = __fadd_rn(r0, __fmul_rn(x[i+0], x[i+0]));
    r1 = __fadd_rn(r1, __fmul_rn(x[i+1], x[i+1]));
    r2 = __fadd_rn(r2, __fmul_rn(x[i+2], x[i+2]));
    r3 = __fadd_rn(r3, __fmul_rn(x[i+3], x[i+3]));
    r4 = __fadd_rn(r4, __fmul_rn(x[i+4], x[i+4]));
    r5 = __fadd_rn(r5, __fmul_rn(x[i+5], x[i+5]));
    r6 = __fadd_rn(r6, __fmul_rn(x[i+6], x[i+6]));
    r7 = __fadd_rn(r7, __fmul_rn(x[i+7], x[i+7]));
  }
  return __fadd_rn(__fadd_rn(__fadd_rn(r0, r1), __fadd_rn(r2, r3)),
                   __fadd_rn(__fadd_rn(r4, r5), __fadd_rn(r6, r7)));
}
__device__ __forceinline__ float np_sumsq256(const float* __restrict__ x) {
  return __fadd_rn(np_sumsq128(x), np_sumsq128(x + 128));
}

// ---------------------------------------------------------------------------
// k_pre: fused [cast_z | cast_cb | prep] by blockIdx range (fewer launches)
// ---------------------------------------------------------------------------
__global__ void k_pre(const float* __restrict__ z, const float* __restrict__ cb,
                      _Float16* __restrict__ Ah, _Float16* __restrict__ Bh,
                      float* __restrict__ sc,
                      double* __restrict__ loss_accum, int* __restrict__ rc) {
  const int bid = blockIdx.x;
  const int tid = threadIdx.x;
  if (bid < 1024) {
    // ---- transpose-cast z (B,D,T) f32 -> Ah (M,D) f16
    __shared__ _Float16 tile[64][64 + 8];
    const int b  = bid >> 7;
    const int dt = (bid >> 5) & 3;
    const int tt = bid & 31;
    const int d0 = dt * 64, t0 = tt * 64;
    const float* zb = z + ((size_t)b * Dd + d0) * Tt + t0;
    #pragma unroll
    for (int p = 0; p < 4; ++p) {
      const int d  = p * 16 + (tid >> 4);
      const int tl = (tid & 15) * 4;
      const float4 v = *(const float4*)(zb + (size_t)d * Tt + tl);
      tile[tl+0][d] = (_Float16)v.x;
      tile[tl+1][d] = (_Float16)v.y;
      tile[tl+2][d] = (_Float16)v.z;
      tile[tl+3][d] = (_Float16)v.w;
    }
    __syncthreads();
    const int r = tid >> 2, seg = tid & 3;
    const int m = b * Tt + t0 + r;
    int4* dst = (int4*)(Ah + (size_t)m * Dd + d0 + seg * 16);
    const int4* srcv = (const int4*)(&tile[r][seg * 16]);
    dst[0] = srcv[0];
    dst[1] = srcv[1];
  } else if (bid < 2048) {
    // ---- cast codebook f32 -> f16, prescaled by 256
    const size_t g = (size_t)(bid - 1024) * 256 + tid;
    const float4 v0 = *(const float4*)(cb + g * 8);
    const float4 v1 = *(const float4*)(cb + g * 8 + 4);
    f16x8 o;
    o[0] = (_Float16)(v0.x * 256.f); o[1] = (_Float16)(v0.y * 256.f);
    o[2] = (_Float16)(v0.z * 256.f); o[3] = (_Float16)(v0.w * 256.f);
    o[4] = (_Float16)(v1.x * 256.f); o[5] = (_Float16)(v1.y * 256.f);
    o[6] = (_Float16)(v1.z * 256.f); o[7] = (_Float16)(v1.w * 256.f);
    *(f16x8*)(Bh + g * 8) = o;
  } else {
    // ---- np-faithful codebook norms (8 lanes own np's 8 acc chains)
    if (bid == 2048 && tid == 0) {
      *loss_accum = 0.0; rc[0] = 0; rc[1] = 0; rc[2] = 0;
    }
    const int gid = (bid - 2048) * 256 + tid;
    const int lane = gid & 63;
    const int j = lane & 7, sub = lane >> 3;
    const int row = (gid >> 6) * 8 + sub;
    if (row >= Kk) return;
    const float* x = cb + (size_t)row * Dd;
    float c0 = __fmul_rn(x[j], x[j]);
    float c1 = __fmul_rn(x[128 + j], x[128 + j]);
    #pragma unroll
    for (int i = 8; i < 128; i += 8) {
      c0 = __fadd_rn(c0, __fmul_rn(x[j + i], x[j + i]));
      c1 = __fadd_rn(c1, __fmul_rn(x[128 + j + i], x[128 + j + i]));
    }
    #pragma unroll
    for (int off = 1; off <= 4; off <<= 1) {
      c0 = __fadd_rn(c0, __shfl_xor(c0, off));
      c1 = __fadd_rn(c1, __shfl_xor(c1, off));
    }
    if (j == 0) sc[row] = __fadd_rn(c0, c1);
  }
}

// ---------------------------------------------------------------------------
// f16 MFMA score pass v15 (128x256, 8 waves, swapped-operand epilogue)
// ---------------------------------------------------------------------------
__global__ __launch_bounds__(512, 4)
void k_mfma(const _Float16* __restrict__ Ah, const _Float16* __restrict__ Bh,
            const float* __restrict__ sc,
            float* __restrict__ pd1, float* __restrict__ pd2, int* __restrict__ pi1) {
  __shared__ __align__(16) _Float16 As[128 * 64];   // 16 KB, dense 128 B rows
  __shared__ __align__(16) _Float16 Bs[256 * 64];   // 32 KB
  __shared__ float mr1[512];
  __shared__ float mr2[512];
  __shared__ int   mri[512];

  const int tid  = threadIdx.x;
  const int bx   = blockIdx.x & 31;      // 32 n-tiles of 256 cols (natural order)
  const int by   = blockIdx.x >> 5;      // 128 m-tiles of 128 rows
  const int m0   = by * 128, n0 = bx * 256;
  const int w    = tid >> 6, lane = tid & 63;
  const int wy   = w >> 2, wx = w & 3;   // 2 row-bands x 4 col-quarters
  const int l15  = lane & 15, quad = lane >> 4;
  const int lhi  = lane >> 3, llo = lane & 7;   // staging roles
  const int p    = llo ^ lhi;                   // swizzled source granule
  const int sw   = l15 & 7;                     // read-side swizzle key

  f32x4 acc[4][4];
  #pragma unroll
  for (int mi = 0; mi < 4; ++mi)
    #pragma unroll
    for (int ni = 0; ni < 4; ++ni)
      acc[mi][ni] = (f32x4){0.f, 0.f, 0.f, 0.f};

  // ---- K loop: per kc stage A (128x64) + B (256x64), then 2 ks x 16 MFMA
  for (int kc = 0; kc < 4; ++kc) {
    __syncthreads();                           // prior LDS reads done
    #pragma unroll
    for (int i = 0; i < 2; ++i) {              // A: 16 chunks of 8 rows x 128 B
      const int c  = w * 2 + i;
      const int r8 = c * 8 + lhi;
      gld16(Ah + (size_t)(m0 + r8) * Dd + kc * 64 + p * 8, As + c * 512);
    }
    #pragma unroll
    for (int i = 0; i < 4; ++i) {              // B: 32 chunks
      const int c  = w * 4 + i;
      const int r8 = c * 8 + lhi;
      gld16(Bh + (size_t)(n0 + r8) * Dd + kc * 64 + p * 8, Bs + c * 512);
    }
    __syncthreads();                           // drains vmcnt -> data visible
    #pragma unroll
    for (int ks = 0; ks < 2; ++ks) {
      f16x8 af[4], bf[4];
      #pragma unroll
      for (int mi = 0; mi < 4; ++mi)
        af[mi] = *(const f16x8*)(As + (wy*64 + mi*16 + l15) * 64 + (((ks*4 + quad) ^ sw) * 8));
      #pragma unroll
      for (int ni = 0; ni < 4; ++ni)
        bf[ni] = *(const f16x8*)(Bs + (wx*64 + ni*16 + l15) * 64 + (((ks*4 + quad) ^ sw) * 8));
      // SWAPPED operands: D[code][zrow]; same dot, same chain -> bit-identical
      #pragma unroll
      for (int mi = 0; mi < 4; ++mi)
        #pragma unroll
        for (int ni = 0; ni < 4; ++ni)
          acc[mi][ni] = __builtin_amdgcn_mfma_f32_16x16x32_f16(bf[ni], af[mi], acc[mi][ni], 0, 0, 0);
    }
  }

  // ---- epilogue: lane = z-row (l15); codes in-register (ni*16 + quad*4 + r)
  float scv[4][4];
  #pragma unroll
  for (int ni = 0; ni < 4; ++ni)
    *(float4*)&scv[ni][0] = *(const float4*)(sc + n0 + wx * 64 + ni * 16 + quad * 4);

  float s1[4], s2[4]; int i1[4];
  #pragma unroll
  for (int mi = 0; mi < 4; ++mi) {
    float a1 = INFINITY, a2 = INFINITY; int ai = 0x7fffffff;
    #pragma unroll
    for (int ni = 0; ni < 4; ++ni)
      #pragma unroll
      for (int r = 0; r < 4; ++r) {            // (ni,r) ascending -> k ascending
        const float sv = fmaf(-0.0078125f, acc[mi][ni][r], scv[ni][r]);  // -2/256
        const int   k  = n0 + wx * 64 + ni * 16 + quad * 4 + r;
        if (sv < a1) { a2 = a1; a1 = sv; ai = k; }
        else if (sv < a2) a2 = sv;
      }
    s1[mi] = a1; s2[mi] = a2; i1[mi] = ai;
  }

  // fold across the 4 quad-groups (codes quad*4+r) -- 2 shuffle steps x 4 q
  #pragma unroll
  for (int off = 16; off <= 32; off <<= 1)
    #pragma unroll
    for (int q = 0; q < 4; ++q) {
      const float o1 = __shfl_xor(s1[q], off);
      const float o2 = __shfl_xor(s2[q], off);
      const int   oi = __shfl_xor(i1[q], off);
      const float n2 = fminf(fminf(s2[q], o2), fmaxf(s1[q], o1));
      if (o1 < s1[q] || (o1 == s1[q] && oi < i1[q])) { s1[q] = o1; i1[q] = oi; }
      s2[q] = n2;
    }

  // merge the 4 wx col-quarters via LDS
  if (quad == 0) {
    #pragma unroll
    for (int mi = 0; mi < 4; ++mi) {
      const int ml = wy * 64 + mi * 16 + l15;  // 0..127
      mr1[ml * 4 + wx] = s1[mi];
      mr2[ml * 4 + wx] = s2[mi];
      mri[ml * 4 + wx] = i1[mi];
    }
  }
  __syncthreads();
  if (tid < 128) {
    float a1 = INFINITY, a2 = INFINITY; int ai = 0x7fffffff;
    #pragma unroll
    for (int x = 0; x < 4; ++x) {              // wx ascending -> k ascending
      const float b1 = mr1[tid * 4 + x], b2 = mr2[tid * 4 + x];
      const int   bi = mri[tid * 4 + x];
      if (b1 < a1 || (b1 == a1 && bi < ai)) { a2 = fminf(a1, b2); a1 = b1; ai = bi; }
      else a2 = fminf(a2, b1);
    }
    const size_t o = (size_t)bx * Mm + (size_t)(m0 + tid);  // split = 256-col window
    pd1[o] = a1; pd2[o] = a2; pi1[o] = ai;
  }
}

// ---------------------------------------------------------------------------
// combine the NSPL partials per row; flag near-ties (slim: no pair emission)
// ---------------------------------------------------------------------------
__global__ void k_combine(const float* __restrict__ pd1, const float* __restrict__ pd2,
                          const int* __restrict__ pi1, int* __restrict__ idxf,
                          int* __restrict__ rc, int* __restrict__ rlist,
                          float* __restrict__ rthr, int* __restrict__ posm,
                          int* __restrict__ slist, float* __restrict__ outIdx) {
  const int m = blockIdx.x * 64 + threadIdx.x;
  if (m >= Mm) return;
  float a1 = INFINITY, a2 = INFINITY; int ai = 0x7fffffff;
  #pragma unroll
  for (int spl = 0; spl < NSPL; ++spl) {         // spl ascending -> k ascending
    const size_t o = (size_t)spl * Mm + m;
    const float b1 = pd1[o], b2 = pd2[o]; const int bi = pi1[o];
    if (b1 < a1 || (b1 == a1 && bi < ai)) { a2 = fminf(a1, b2); a1 = b1; ai = bi; }
    else a2 = fminf(a2, b1);
  }
  idxf[m]   = ai;
  outIdx[m] = (float)ai;
  int pos = -1;
  if (a2 - a1 <= RESCAN_MARGIN) {
    const int p = atomicAdd(&rc[0], 1);
    if (p < ZG_CAP) {
      rlist[p] = m;
      rthr[p]  = a1 + RESCAN_MARGIN;
      pos = p;
    } else {
      // zg overflow: full slow scan for this row
      const int s = atomicAdd(&rc[2], 1); slist[s] = m;
    }
  }
  posm[m] = pos;
}

// ---------------------------------------------------------------------------
// gather flagged rows into compact zg; np norms (8-lane parallel, same tree
// as k_pre's norm branch); init packed minima
// ---------------------------------------------------------------------------
__global__ void k_gather(const float* __restrict__ z, const int* __restrict__ rc,
                         const int* __restrict__ rlist, float* __restrict__ zg,
                         float* __restrict__ Ag, unsigned long long* __restrict__ pbrow) {
  __shared__ float zr[Dd];
  const int cnt = min(rc[0], ZG_CAP);
  const int tid = threadIdx.x;
  for (int it = blockIdx.x; it < cnt; it += gridDim.x) {
    const int m = rlist[it];
    const int b = m / Tt, t = m & (Tt - 1);
    __syncthreads();
    zr[tid] = z[(size_t)b * Dd * Tt + (size_t)tid * Tt + t];
    __syncthreads();
    zg[(size_t)it * Dd + tid] = zr[tid];
    if (tid < 8) {
      const int j = tid;
      float c0 = __fmul_rn(zr[j], zr[j]);
      float c1 = __fmul_rn(zr[128 + j], zr[128 + j]);
      #pragma unroll
      for (int i = 8; i < 128; i += 8) {
        c0 = __fadd_rn(c0, __fmul_rn(zr[j + i], zr[j + i]));
        c1 = __fadd_rn(c1, __fmul_rn(zr[128 + j + i], zr[128 + j + i]));
      }
      #pragma unroll
      for (int off = 1; off <= 4; off <<= 1) {
        c0 = __fadd_rn(c0, __shfl_xor(c0, off));
        c1 = __fadd_rn(c1, __shfl_xor(c1, off));
      }
      if (j == 0) { Ag[it] = __fadd_rn(c0, c1); pbrow[it] = ~0ull; }
    }
  }
}

// ---------------------------------------------------------------------------
// exact rescan of one candidate: np-faithful fp64 dot (same segment grouping
// and rounding sequence as always), packed (orderable f32, idx).
// ---------------------------------------------------------------------------
__device__ __forceinline__ unsigned long long cand_pack(
    const float* __restrict__ cb, const float* __restrict__ sc,
    const float* __restrict__ zp, const float Az, const int k) {
  const float* __restrict__ cp = cb + (size_t)k * Dd;
  double M8 = 0.0;
  #pragma unroll
  for (int sg = 0; sg < 8; ++sg) {
    double a0 = 0.0, a1 = 0.0, a2 = 0.0, a3 = 0.0;
    #pragma unroll
    for (int j = 0; j < 32; j += 4) {
      const float4 c4 = *(const float4*)(cp + sg * 32 + j);
      const float4 z4 = *(const float4*)(zp + sg * 32 + j);
      a0 = fma((double)c4.x, (double)z4.x, a0);
      a1 = fma((double)c4.y, (double)z4.y, a1);
      a2 = fma((double)c4.z, (double)z4.z, a2);
      a3 = fma((double)c4.w, (double)z4.w, a3);
    }
    M8 += (a0 + a1) + (a2 + a3);
  }
  const float M  = (float)M8;
  const float t1 = __fsub_rn(Az, __fmul_rn(2.0f, M));
  const float dq = __fadd_rn(t1, sc[k]);
  unsigned int fb = __float_as_uint(dq);
  fb = (fb & 0x80000000u) ? ~fb : (fb | 0x80000000u);
  return ((unsigned long long)fb << 32) | (unsigned)k;
}

// ---------------------------------------------------------------------------
// wave-per-row rescan: lanes 0..31 scan the splits; a lane whose split has a
// single near-tie winner rescans it DIRECTLY (lockstep-parallel across the
// wave). Dump-splits (pd2<=thr) are PUSHED to dlist for k_rescan_dumps.
// ---------------------------------------------------------------------------
__global__ __launch_bounds__(256)
void k_rescan_rows(const float* __restrict__ cb, const float* __restrict__ sc,
                   int* __restrict__ rc, const int* __restrict__ rlist,
                   const float* __restrict__ rthr,
                   const float* __restrict__ pd1, const float* __restrict__ pd2,
                   const int* __restrict__ pi1,
                   const float* __restrict__ zg, const float* __restrict__ Ag,
                   int* __restrict__ dlist,
                   unsigned long long* __restrict__ pbrow) {
  const int cnt  = min(rc[0], ZG_CAP);
  const int wv   = threadIdx.x >> 6;
  const int lane = threadIdx.x & 63;
  const int it   = blockIdx.x * 4 + wv;
  if (it >= cnt) return;
  const int   m   = rlist[it];
  const float thr = rthr[it];
  const float Az  = Ag[it];
  const float* __restrict__ zp = zg + (size_t)it * Dd;

  int cand = -1;
  if (lane < NSPL) {
    const size_t o = (size_t)lane * Mm + m;
    const float b1 = pd1[o], b2 = pd2[o];
    if (b2 <= thr) {                            // rare; parallelized downstream
      const int dq = atomicAdd(&rc[1], 1);
      if (dq < DUMP_CAP) dlist[dq] = (it << 5) | lane;
    } else if (b1 <= thr) {
      cand = pi1[o];
    }
  }
  if (cand >= 0)
    atomicMin(pbrow + it, cand_pack(cb, sc, zp, Az, cand));
}

// ---------------------------------------------------------------------------
// dump rescan: one (row,split) entry per BLOCK, one code per thread.
// 32-lane-half shuffle reduce (offsets 16..1 only -- the R7-proven idiom),
// one atomicMin per half. No serial tails.
// ---------------------------------------------------------------------------
__global__ __launch_bounds__(256)
void k_rescan_dumps(const float* __restrict__ cb, const float* __restrict__ sc,
                    const int* __restrict__ rc, const int* __restrict__ dlist,
                    const float* __restrict__ zg, const float* __restrict__ Ag,
                    unsigned long long* __restrict__ pbrow) {
  const int nd = min(rc[1], DUMP_CAP);
  for (int e = blockIdx.x; e < nd; e += gridDim.x) {
    const int ent = dlist[e];
    const int it = ent >> 5, spl = ent & 31;
    const int k  = spl * 256 + threadIdx.x;
    unsigned long long pk =
        cand_pack(cb, sc, zg + (size_t)it * Dd, Ag[it], k);
    #pragma unroll
    for (int off = 16; off; off >>= 1) {
      const unsigned long long o = __shfl_xor(pk, off);
      if (o < pk) pk = o;
    }
    if ((threadIdx.x & 31) == 0) atomicMin(pbrow + it, pk);
  }
}

// overflow fallback: normally 0 iterations
__global__ void k_rescan_slow(const float* __restrict__ z, const float* __restrict__ cb,
                              const float* __restrict__ sc,
                              const int* __restrict__ rc, const int* __restrict__ slist,
                              int* __restrict__ idxf, float* __restrict__ outIdx) {
  __shared__ float zrow[Dd];
  __shared__ float Ash;
  __shared__ float sval[256];
  __shared__ int   sidx[256];
  const int tid = threadIdx.x;
  const int cnt = rc[2];
  for (int it = blockIdx.x; it < cnt; it += gridDim.x) {
    const int m = slist[it];
    const int b = m / Tt, t = m & (Tt - 1);
    __syncthreads();
    zrow[tid] = z[(size_t)b * Dd * Tt + (size_t)tid * Tt + t];
    __syncthreads();
    if (tid == 0) Ash = np_sumsq256(zrow);
    __syncthreads();
    const float A = Ash;
    float best = INFINITY; int bi = 0x7fffffff;
    for (int k = tid; k < Kk; k += 256) {
      const float* cr = cb + (size_t)k * Dd;
      double a0 = 0.0, a1 = 0.0, a2 = 0.0, a3 = 0.0;
      for (int d = 0; d < Dd; d += 4) {
        const float4 c4 = *(const float4*)(cr + d);
        a0 = fma((double)c4.x, (double)zrow[d+0], a0);
        a1 = fma((double)c4.y, (double)zrow[d+1], a1);
        a2 = fma((double)c4.z, (double)zrow[d+2], a2);
        a3 = fma((double)c4.w, (double)zrow[d+3], a3);
      }
      const float M  = (float)((a0 + a1) + (a2 + a3));
      const float t1 = __fsub_rn(A, __fmul_rn(2.0f, M));
      const float dq = __fadd_rn(t1, sc[k]);
      if (dq < best) { best = dq; bi = k; }
    }
    sval[tid] = best; sidx[tid] = bi;
    __syncthreads();
    for (int off = 128; off; off >>= 1) {
      if (tid < off) {
        if (sval[tid+off] < sval[tid] ||
            (sval[tid+off] == sval[tid] && sidx[tid+off] < sidx[tid])) {
          sval[tid] = sval[tid+off]; sidx[tid] = sidx[tid+off];
        }
      }
      __syncthreads();
    }
    if (tid == 0) { idxf[m] = sidx[0]; outIdx[m] = (float)sidx[0]; }
    __syncthreads();
  }
}

// ---------------------------------------------------------------------------
// fused gather + transpose + STE + loss + final index resolution:
// out[b][d][t] = z + (cb[idx] - z); idx = pbrow result for rescanned rows.
// ---------------------------------------------------------------------------
__global__ void k_out(const float* __restrict__ z, const float* __restrict__ cb,
                      const int* __restrict__ idxf, const int* __restrict__ posm,
                      const unsigned long long* __restrict__ pbrow,
                      float* __restrict__ outZ, float* __restrict__ outIdx,
                      double* __restrict__ loss_accum) {
  __shared__ float tile[64][65];          // [d][t]
  const int tid = threadIdx.x;
  const int bidx = blockIdx.x;            // 8 * 4 * 32 = 1024
  const int b  = bidx >> 7;
  const int dt = (bidx >> 5) & 3;
  const int tt = bidx & 31;
  const int d0 = dt * 64, t0 = tt * 64;
  {
    const int r = tid >> 2, seg = tid & 3;
    const int m = b * Tt + t0 + r;
    int idx = idxf[m];
    const int pos = posm[m];
    if (pos >= 0) {
      const unsigned long long pb = pbrow[pos];
      if (pb != ~0ull) {
        idx = (int)(unsigned)(pb & 0xFFFFFFFFull);
        if (seg == 0) outIdx[m] = (float)idx;
      }
    }
    const float* src = cb + (size_t)idx * Dd + d0 + seg * 16;
    #pragma unroll
    for (int q4 = 0; q4 < 4; ++q4) {
      const float4 v = *(const float4*)(src + q4 * 4);
      tile[seg * 16 + q4 * 4 + 0][r] = v.x;
      tile[seg * 16 + q4 * 4 + 1][r] = v.y;
      tile[seg * 16 + q4 * 4 + 2][r] = v.z;
      tile[seg * 16 + q4 * 4 + 3][r] = v.w;
    }
  }
  __syncthreads();
  const float* zbase = z + ((size_t)b * Dd + d0) * Tt + t0;
  float*       obase = outZ + ((size_t)b * Dd + d0) * Tt + t0;
  double ls = 0.0;
  #pragma unroll
  for (int p = 0; p < 4; ++p) {
    const int d  = p * 16 + (tid >> 4);
    const int t4 = (tid & 15) * 4;
    const float4 zv = *(const float4*)(zbase + (size_t)d * Tt + t4);
    const float q0 = tile[d][t4+0], q1 = tile[d][t4+1];
    const float q2 = tile[d][t4+2], q3 = tile[d][t4+3];
    const float r0 = q0 - zv.x, r1 = q1 - zv.y, r2 = q2 - zv.z, r3 = q3 - zv.w;
    float4 o;
    o.x = zv.x + r0; o.y = zv.y + r1; o.z = zv.z + r2; o.w = zv.w + r3;
    *(float4*)(obase + (size_t)d * Tt + t4) = o;
    ls += (double)r0*r0 + (double)r1*r1 + (double)r2*r2 + (double)r3*r3;
  }
  #pragma unroll
  for (int off = 32; off; off >>= 1) ls += __shfl_down(ls, off);
  if ((tid & 63) == 0) atomicAdd(loss_accum, ls);
}

__global__ void k_finalize(const double* __restrict__ loss_accum, float* __restrict__ outLoss) {
  const double mean = *loss_accum / (double)((size_t)Bz * Dd * Tt);
  *outLoss = (float)(mean + 0.1 * mean);
}

// ---------------------------------------------------------------------------
extern "C" void kernel_launch(void* const* d_in, const int* in_sizes, int n_in,
                              void* d_out, int out_size, void* d_ws, size_t ws_size,
                              hipStream_t stream) {
  (void)in_sizes; (void)n_in; (void)out_size; (void)ws_size;
  const float* z  = (const float*)d_in[0];   // (B, D, T) fp32
  const float* cb = (const float*)d_in[1];   // (K, D)    fp32

  float* outZ    = (float*)d_out;
  float* outIdx  = outZ + (size_t)Bz * Dd * Tt;
  float* outLoss = outIdx + Mm;

  char* w = (char*)d_ws;
  double*    loss_accum = (double*)w;    w += 16;
  int*       rc         = (int*)w;       w += 16;   // [0]=rows [1]=dumps [2]=slow
  int*       rlist      = (int*)w;       w += sizeof(int)   * Mm;
  int*       slist      = (int*)w;       w += sizeof(int)   * Mm;
  int*       idxf       = (int*)w;       w += sizeof(int)   * Mm;
  int*       posm       = (int*)w;       w += sizeof(int)   * Mm;
  float*     sc         = (float*)w;     w += sizeof(float) * Kk;
  float*     rthr       = (float*)w;     w += sizeof(float) * ZG_CAP;
  int*       dlist      = (int*)w;       w += sizeof(int)   * DUMP_CAP;
  _Float16*  Ah         = (_Float16*)w;  w += sizeof(_Float16) * (size_t)Mm * Dd;
  _Float16*  Bh         = (_Float16*)w;  w += sizeof(_Float16) * (size_t)Kk * Dd;
  float*     zg         = (float*)w;     w += sizeof(float) * (size_t)ZG_CAP * Dd;
  float*     Ag         = (float*)w;     w += sizeof(float) * ZG_CAP;
  unsigned long long* pbrow = (unsigned long long*)w; w += sizeof(unsigned long long) * ZG_CAP;
  float*     pd1        = (float*)w;     w += sizeof(float) * (size_t)NSPL * Mm;
  float*     pd2        = (float*)w;     w += sizeof(float) * (size_t)NSPL * Mm;
  int*       pi1        = (int*)w;       /* total ~24 MB */

  k_pre          <<<dim3(2304), 256, 0, stream>>>(z, cb, Ah, Bh, sc, loss_accum, rc);
  k_mfma         <<<dim3((Mm / 128) * (Kk / 256)), 512, 0, stream>>>(Ah, Bh, sc, pd1, pd2, pi1);
  k_combine      <<<dim3(Mm / 64), 64, 0, stream>>>(pd1, pd2, pi1, idxf, rc, rlist, rthr, posm, slist, outIdx);
  k_gather       <<<dim3(256), 256, 0, stream>>>(z, rc, rlist, zg, Ag, pbrow);
  k_rescan_rows  <<<dim3(ZG_CAP / 4), 256, 0, stream>>>(cb, sc, rc, rlist, rthr, pd1, pd2, pi1, zg, Ag, dlist, pbrow);
  k_rescan_dumps <<<dim3(256), 256, 0, stream>>>(cb, sc, rc, dlist, zg, Ag, pbrow);
  k_rescan_slow  <<<dim3(64), 256, 0, stream>>>(z, cb, sc, rc, slist, idxf, outIdx);
  k_out          <<<dim3(1024), 256, 0, stream>>>(z, cb, idxf, posm, pbrow, outZ, outIdx, loss_accum);
  k_finalize     <<<dim3(1), 1, 0, stream>>>(loss_accum, outLoss);
}

// Round 12
// 278.686 us; speedup vs baseline: 1.2959x; 1.0234x over previous
//
#include <hip/hip_runtime.h>
#include <hip/hip_bf16.h>
#include <float.h>
#include <math.h>

#define Bz 8
#define Dd 256
#define Tt 2048
#define Kk 8192
#define Mm (Bz*Tt)          // 16384 rows (b*T + t)

// Scorer v16: v15 structure with mr merge buffers ALIASED onto As (both uses
// separated by the epilogue barrier) -> LDS 48 KB -> 3 blocks/CU (24 waves).
// Rescan v18: k_gather fused into k_rescan_rows (wave gathers z row into LDS,
// computes np-faithful norm with the k_pre 8-lane chain, writes zg/Ag for the
// dumps kernel); k_combine initializes pbrow. 8 launches total.
#define NSPL 32

#define ZG_CAP 4096
#define DUMP_CAP (ZG_CAP * NSPL)

// Margin: covers f16 fast-pass score error + np fp32 quantization straddle
#define RESCAN_MARGIN 6e-4f

typedef __attribute__((ext_vector_type(8))) _Float16 f16x8;
typedef __attribute__((ext_vector_type(4))) float    f32x4;

// async global->LDS DMA, 16 B per lane; lds dest = wave-uniform base + lane*16
__device__ __forceinline__ void gld16(const void* g, void* l) {
  __builtin_amdgcn_global_load_lds(
      (const __attribute__((address_space(1))) void*)g,
      (__attribute__((address_space(3))) void*)l, 16, 0, 0);
}

// ---------------------------------------------------------------------------
// numpy-faithful pairwise sum of squares (blocksize-128 pairwise, 8 accums)
// ---------------------------------------------------------------------------
__device__ __forceinline__ float np_sumsq128(const float* __restrict__ x) {
  float r0 = __fmul_rn(x[0], x[0]);
  float r1 = __fmul_rn(x[1], x[1]);
  float r2 = __fmul_rn(x[2], x[2]);
  float r3 = __fmul_rn(x[3], x[3]);
  float r4 = __fmul_rn(x[4], x[4]);
  float r5 = __fmul_rn(x[5], x[5]);
  float r6 = __fmul_rn(x[6], x[6]);
  float r7 = __fmul_rn(x[7], x[7]);
  for (int i = 8; i < 128; i += 8) {
    r0 = __fadd_rn(r0, __fmul_rn(x[i+0], x[i+0]));
    r1 = __fadd_rn(r1, __fmul_rn(x[i+1], x[i+1]));
    r2 = __fadd_rn(r2, __fmul_rn(x[i+2], x[i+2]));
    r3 = __fadd_rn(r3, __fmul_rn(x[i+3], x[i+3]));
    r4 = __fadd_rn(r4, __fmul_rn(x[i+4], x[i+4]));
    r5 = __fadd_rn(r5, __fmul_rn(x[i+5], x[i+5]));
    r6 = __fadd_rn(r6, __fmul_rn(x[i+6], x[i+6]));
    r7 = __fadd_rn(r7, __fmul_rn(x[i+7], x[i+7]));
  }
  return __fadd_rn(__fadd_rn(__fadd_rn(r0, r1), __fadd_rn(r2, r3)),
                   __fadd_rn(__fadd_rn(r4, r5), __fadd_rn(r6, r7)));
}
__device__ __forceinline__ float np_sumsq256(const float* __restrict__ x) {
  return __fadd_rn(np_sumsq128(x), np_sumsq128(x + 128));
}

// ---------------------------------------------------------------------------
// k_pre: fused [cast_z | cast_cb | prep] by blockIdx range (fewer launches)
// ---------------------------------------------------------------------------
__global__ void k_pre(const float* __restrict__ z, const float* __restrict__ cb,
                      _Float16* __restrict__ Ah, _Float16* __restrict__ Bh,
                      float* __restrict__ sc,
                      double* __restrict__ loss_accum, int* __restrict__ rc) {
  const int bid = blockIdx.x;
  const int tid = threadIdx.x;
  if (bid < 1024) {
    // ---- transpose-cast z (B,D,T) f32 -> Ah (M,D) f16
    __shared__ _Float16 tile[64][64 + 8];
    const int b  = bid >> 7;
    const int dt = (bid >> 5) & 3;
    const int tt = bid & 31;
    const int d0 = dt * 64, t0 = tt * 64;
    const float* zb = z + ((size_t)b * Dd + d0) * Tt + t0;
    #pragma unroll
    for (int p = 0; p < 4; ++p) {
      const int d  = p * 16 + (tid >> 4);
      const int tl = (tid & 15) * 4;
      const float4 v = *(const float4*)(zb + (size_t)d * Tt + tl);
      tile[tl+0][d] = (_Float16)v.x;
      tile[tl+1][d] = (_Float16)v.y;
      tile[tl+2][d] = (_Float16)v.z;
      tile[tl+3][d] = (_Float16)v.w;
    }
    __syncthreads();
    const int r = tid >> 2, seg = tid & 3;
    const int m = b * Tt + t0 + r;
    int4* dst = (int4*)(Ah + (size_t)m * Dd + d0 + seg * 16);
    const int4* srcv = (const int4*)(&tile[r][seg * 16]);
    dst[0] = srcv[0];
    dst[1] = srcv[1];
  } else if (bid < 2048) {
    // ---- cast codebook f32 -> f16, prescaled by 256
    const size_t g = (size_t)(bid - 1024) * 256 + tid;
    const float4 v0 = *(const float4*)(cb + g * 8);
    const float4 v1 = *(const float4*)(cb + g * 8 + 4);
    f16x8 o;
    o[0] = (_Float16)(v0.x * 256.f); o[1] = (_Float16)(v0.y * 256.f);
    o[2] = (_Float16)(v0.z * 256.f); o[3] = (_Float16)(v0.w * 256.f);
    o[4] = (_Float16)(v1.x * 256.f); o[5] = (_Float16)(v1.y * 256.f);
    o[6] = (_Float16)(v1.z * 256.f); o[7] = (_Float16)(v1.w * 256.f);
    *(f16x8*)(Bh + g * 8) = o;
  } else {
    // ---- np-faithful codebook norms (8 lanes own np's 8 acc chains)
    if (bid == 2048 && tid == 0) {
      *loss_accum = 0.0; rc[0] = 0; rc[1] = 0; rc[2] = 0;
    }
    const int gid = (bid - 2048) * 256 + tid;
    const int lane = gid & 63;
    const int j = lane & 7, sub = lane >> 3;
    const int row = (gid >> 6) * 8 + sub;
    if (row >= Kk) return;
    const float* x = cb + (size_t)row * Dd;
    float c0 = __fmul_rn(x[j], x[j]);
    float c1 = __fmul_rn(x[128 + j], x[128 + j]);
    #pragma unroll
    for (int i = 8; i < 128; i += 8) {
      c0 = __fadd_rn(c0, __fmul_rn(x[j + i], x[j + i]));
      c1 = __fadd_rn(c1, __fmul_rn(x[128 + j + i], x[128 + j + i]));
    }
    #pragma unroll
    for (int off = 1; off <= 4; off <<= 1) {
      c0 = __fadd_rn(c0, __shfl_xor(c0, off));
      c1 = __fadd_rn(c1, __shfl_xor(c1, off));
    }
    if (j == 0) sc[row] = __fadd_rn(c0, c1);
  }
}

// ---------------------------------------------------------------------------
// f16 MFMA score pass v16 (128x256, 8 waves, swapped-operand epilogue,
// mr aliased onto As -> 48 KB LDS -> 3 blocks/CU)
// ---------------------------------------------------------------------------
__global__ __launch_bounds__(512, 4)
void k_mfma(const _Float16* __restrict__ Ah, const _Float16* __restrict__ Bh,
            const float* __restrict__ sc,
            float* __restrict__ pd1, float* __restrict__ pd2, int* __restrict__ pi1) {
  __shared__ __align__(16) _Float16 As[128 * 64];   // 16 KB; epilogue reuses as mr
  __shared__ __align__(16) _Float16 Bs[256 * 64];   // 32 KB
  float* mr1 = reinterpret_cast<float*>(As);        // 2 KB  (after barrier only)
  float* mr2 = mr1 + 512;                           // 2 KB
  int*   mri = reinterpret_cast<int*>(mr1 + 1024);  // 2 KB

  const int tid  = threadIdx.x;
  const int bx   = blockIdx.x & 31;      // 32 n-tiles of 256 cols (natural order)
  const int by   = blockIdx.x >> 5;      // 128 m-tiles of 128 rows
  const int m0   = by * 128, n0 = bx * 256;
  const int w    = tid >> 6, lane = tid & 63;
  const int wy   = w >> 2, wx = w & 3;   // 2 row-bands x 4 col-quarters
  const int l15  = lane & 15, quad = lane >> 4;
  const int lhi  = lane >> 3, llo = lane & 7;   // staging roles
  const int p    = llo ^ lhi;                   // swizzled source granule
  const int sw   = l15 & 7;                     // read-side swizzle key

  f32x4 acc[4][4];
  #pragma unroll
  for (int mi = 0; mi < 4; ++mi)
    #pragma unroll
    for (int ni = 0; ni < 4; ++ni)
      acc[mi][ni] = (f32x4){0.f, 0.f, 0.f, 0.f};

  // ---- K loop: per kc stage A (128x64) + B (256x64), then 2 ks x 16 MFMA
  for (int kc = 0; kc < 4; ++kc) {
    __syncthreads();                           // prior LDS reads done
    #pragma unroll
    for (int i = 0; i < 2; ++i) {              // A: 16 chunks of 8 rows x 128 B
      const int c  = w * 2 + i;
      const int r8 = c * 8 + lhi;
      gld16(Ah + (size_t)(m0 + r8) * Dd + kc * 64 + p * 8, As + c * 512);
    }
    #pragma unroll
    for (int i = 0; i < 4; ++i) {              // B: 32 chunks
      const int c  = w * 4 + i;
      const int r8 = c * 8 + lhi;
      gld16(Bh + (size_t)(n0 + r8) * Dd + kc * 64 + p * 8, Bs + c * 512);
    }
    __syncthreads();                           // drains vmcnt -> data visible
    #pragma unroll
    for (int ks = 0; ks < 2; ++ks) {
      f16x8 af[4], bf[4];
      #pragma unroll
      for (int mi = 0; mi < 4; ++mi)
        af[mi] = *(const f16x8*)(As + (wy*64 + mi*16 + l15) * 64 + (((ks*4 + quad) ^ sw) * 8));
      #pragma unroll
      for (int ni = 0; ni < 4; ++ni)
        bf[ni] = *(const f16x8*)(Bs + (wx*64 + ni*16 + l15) * 64 + (((ks*4 + quad) ^ sw) * 8));
      // SWAPPED operands: D[code][zrow]; same dot, same chain -> bit-identical
      #pragma unroll
      for (int mi = 0; mi < 4; ++mi)
        #pragma unroll
        for (int ni = 0; ni < 4; ++ni)
          acc[mi][ni] = __builtin_amdgcn_mfma_f32_16x16x32_f16(bf[ni], af[mi], acc[mi][ni], 0, 0, 0);
    }
  }

  // ---- epilogue: lane = z-row (l15); codes in-register (ni*16 + quad*4 + r)
  float scv[4][4];
  #pragma unroll
  for (int ni = 0; ni < 4; ++ni)
    *(float4*)&scv[ni][0] = *(const float4*)(sc + n0 + wx * 64 + ni * 16 + quad * 4);

  float s1[4], s2[4]; int i1[4];
  #pragma unroll
  for (int mi = 0; mi < 4; ++mi) {
    float a1 = INFINITY, a2 = INFINITY; int ai = 0x7fffffff;
    #pragma unroll
    for (int ni = 0; ni < 4; ++ni)
      #pragma unroll
      for (int r = 0; r < 4; ++r) {            // (ni,r) ascending -> k ascending
        const float sv = fmaf(-0.0078125f, acc[mi][ni][r], scv[ni][r]);  // -2/256
        const int   k  = n0 + wx * 64 + ni * 16 + quad * 4 + r;
        if (sv < a1) { a2 = a1; a1 = sv; ai = k; }
        else if (sv < a2) a2 = sv;
      }
    s1[mi] = a1; s2[mi] = a2; i1[mi] = ai;
  }

  // fold across the 4 quad-groups (codes quad*4+r) -- 2 shuffle steps x 4 q
  #pragma unroll
  for (int off = 16; off <= 32; off <<= 1)
    #pragma unroll
    for (int q = 0; q < 4; ++q) {
      const float o1 = __shfl_xor(s1[q], off);
      const float o2 = __shfl_xor(s2[q], off);
      const int   oi = __shfl_xor(i1[q], off);
      const float n2 = fminf(fminf(s2[q], o2), fmaxf(s1[q], o1));
      if (o1 < s1[q] || (o1 == s1[q] && oi < i1[q])) { s1[q] = o1; i1[q] = oi; }
      s2[q] = n2;
    }

  // merge the 4 wx col-quarters via LDS (mr aliases As: barrier orders uses)
  __syncthreads();                             // all As/Bs reads done
  if (quad == 0) {
    #pragma unroll
    for (int mi = 0; mi < 4; ++mi) {
      const int ml = wy * 64 + mi * 16 + l15;  // 0..127
      mr1[ml * 4 + wx] = s1[mi];
      mr2[ml * 4 + wx] = s2[mi];
      mri[ml * 4 + wx] = i1[mi];
    }
  }
  __syncthreads();
  if (tid < 128) {
    float a1 = INFINITY, a2 = INFINITY; int ai = 0x7fffffff;
    #pragma unroll
    for (int x = 0; x < 4; ++x) {              // wx ascending -> k ascending
      const float b1 = mr1[tid * 4 + x], b2 = mr2[tid * 4 + x];
      const int   bi = mri[tid * 4 + x];
      if (b1 < a1 || (b1 == a1 && bi < ai)) { a2 = fminf(a1, b2); a1 = b1; ai = bi; }
      else a2 = fminf(a2, b1);
    }
    const size_t o = (size_t)bx * Mm + (size_t)(m0 + tid);  // split = 256-col window
    pd1[o] = a1; pd2[o] = a2; pi1[o] = ai;
  }
}

// ---------------------------------------------------------------------------
// combine the NSPL partials per row; flag near-ties; init pbrow slot
// ---------------------------------------------------------------------------
__global__ void k_combine(const float* __restrict__ pd1, const float* __restrict__ pd2,
                          const int* __restrict__ pi1, int* __restrict__ idxf,
                          int* __restrict__ rc, int* __restrict__ rlist,
                          float* __restrict__ rthr, int* __restrict__ posm,
                          int* __restrict__ slist, unsigned long long* __restrict__ pbrow,
                          float* __restrict__ outIdx) {
  const int m = blockIdx.x * 64 + threadIdx.x;
  if (m >= Mm) return;
  float a1 = INFINITY, a2 = INFINITY; int ai = 0x7fffffff;
  #pragma unroll
  for (int spl = 0; spl < NSPL; ++spl) {         // spl ascending -> k ascending
    const size_t o = (size_t)spl * Mm + m;
    const float b1 = pd1[o], b2 = pd2[o]; const int bi = pi1[o];
    if (b1 < a1 || (b1 == a1 && bi < ai)) { a2 = fminf(a1, b2); a1 = b1; ai = bi; }
    else a2 = fminf(a2, b1);
  }
  idxf[m]   = ai;
  outIdx[m] = (float)ai;
  int pos = -1;
  if (a2 - a1 <= RESCAN_MARGIN) {
    const int p = atomicAdd(&rc[0], 1);
    if (p < ZG_CAP) {
      rlist[p] = m;
      rthr[p]  = a1 + RESCAN_MARGIN;
      pbrow[p] = ~0ull;
      pos = p;
    } else {
      // zg overflow: full slow scan for this row
      const int s = atomicAdd(&rc[2], 1); slist[s] = m;
    }
  }
  posm[m] = pos;
}

// ---------------------------------------------------------------------------
// exact rescan of one candidate: np-faithful fp64 dot (same segment grouping
// and rounding sequence as always), packed (orderable f32, idx).
// ---------------------------------------------------------------------------
__device__ __forceinline__ unsigned long long cand_pack(
    const float* __restrict__ cb, const float* __restrict__ sc,
    const float* zp, const float Az, const int k) {
  const float* __restrict__ cp = cb + (size_t)k * Dd;
  double M8 = 0.0;
  #pragma unroll
  for (int sg = 0; sg < 8; ++sg) {
    double a0 = 0.0, a1 = 0.0, a2 = 0.0, a3 = 0.0;
    #pragma unroll
    for (int j = 0; j < 32; j += 4) {
      const float4 c4 = *(const float4*)(cp + sg * 32 + j);
      const float4 z4 = *(const float4*)(zp + sg * 32 + j);
      a0 = fma((double)c4.x, (double)z4.x, a0);
      a1 = fma((double)c4.y, (double)z4.y, a1);
      a2 = fma((double)c4.z, (double)z4.z, a2);
      a3 = fma((double)c4.w, (double)z4.w, a3);
    }
    M8 += (a0 + a1) + (a2 + a3);
  }
  const float M  = (float)M8;
  const float t1 = __fsub_rn(Az, __fmul_rn(2.0f, M));
  const float dq = __fadd_rn(t1, sc[k]);
  unsigned int fb = __float_as_uint(dq);
  fb = (fb & 0x80000000u) ? ~fb : (fb | 0x80000000u);
  return ((unsigned long long)fb << 32) | (unsigned)k;
}

// ---------------------------------------------------------------------------
// wave-per-row rescan with FUSED gather: the wave loads the z row into LDS,
// computes the np-faithful norm (k_pre's proven 8-lane chain + shuffle tree),
// writes zg/Ag for the dumps kernel, then scans splits. Single-winner
// candidates rescanned directly per lane; dump-splits pushed to dlist.
// All threads reach the barrier (no early return before it).
// ---------------------------------------------------------------------------
__global__ __launch_bounds__(256)
void k_rescan_rows(const float* __restrict__ z, const float* __restrict__ cb,
                   const float* __restrict__ sc,
                   int* __restrict__ rc, const int* __restrict__ rlist,
                   const float* __restrict__ rthr,
                   const float* __restrict__ pd1, const float* __restrict__ pd2,
                   const int* __restrict__ pi1,
                   float* __restrict__ zg, float* __restrict__ Ag,
                   int* __restrict__ dlist,
                   unsigned long long* __restrict__ pbrow) {
  __shared__ __align__(16) float zrb[4][Dd];
  const int cnt  = min(rc[0], ZG_CAP);
  const int wv   = threadIdx.x >> 6;
  const int lane = threadIdx.x & 63;
  const int it   = blockIdx.x * 4 + wv;
  const bool act = (it < cnt);
  int m = 0;
  if (act) {
    m = rlist[it];
    const int b = m / Tt, t = m & (Tt - 1);
    #pragma unroll
    for (int i = 0; i < 4; ++i) {
      const int d = i * 64 + lane;
      const float v = z[(size_t)b * Dd * Tt + (size_t)d * Tt + t];
      zrb[wv][d] = v;
      zg[(size_t)it * Dd + d] = v;
    }
  }
  __syncthreads();
  if (!act) return;

  // np-faithful norm (same chains + shuffle tree as k_pre's sc — proven)
  float c0 = 0.f, c1 = 0.f;
  if (lane < 8) {
    const int j = lane;
    const float* x = zrb[wv];
    c0 = __fmul_rn(x[j], x[j]);
    c1 = __fmul_rn(x[128 + j], x[128 + j]);
    #pragma unroll
    for (int i = 8; i < 128; i += 8) {
      c0 = __fadd_rn(c0, __fmul_rn(x[j + i], x[j + i]));
      c1 = __fadd_rn(c1, __fmul_rn(x[128 + j + i], x[128 + j + i]));
    }
  }
  #pragma unroll
  for (int off = 1; off <= 4; off <<= 1) {
    c0 = __fadd_rn(c0, __shfl_xor(c0, off));
    c1 = __fadd_rn(c1, __shfl_xor(c1, off));
  }
  const float AzL = __fadd_rn(c0, c1);           // valid on lane 0
  const float Az  = __shfl(AzL, 0);
  if (lane == 0) Ag[it] = Az;

  const float thr = rthr[it];
  int cand = -1;
  if (lane < NSPL) {
    const size_t o = (size_t)lane * Mm + m;
    const float b1 = pd1[o], b2 = pd2[o];
    if (b2 <= thr) {                            // rare; parallelized downstream
      const int dq = atomicAdd(&rc[1], 1);
      if (dq < DUMP_CAP) dlist[dq] = (it << 5) | lane;
    } else if (b1 <= thr) {
      cand = pi1[o];
    }
  }
  if (cand >= 0)
    atomicMin(pbrow + it, cand_pack(cb, sc, zrb[wv], Az, cand));
}

// ---------------------------------------------------------------------------
// dump rescan: one (row,split) entry per BLOCK, one code per thread.
// 32-lane-half shuffle reduce (offsets 16..1), one atomicMin per half.
// ---------------------------------------------------------------------------
__global__ __launch_bounds__(256)
void k_rescan_dumps(const float* __restrict__ cb, const float* __restrict__ sc,
                    const int* __restrict__ rc, const int* __restrict__ dlist,
                    const float* __restrict__ zg, const float* __restrict__ Ag,
                    unsigned long long* __restrict__ pbrow) {
  const int nd = min(rc[1], DUMP_CAP);
  for (int e = blockIdx.x; e < nd; e += gridDim.x) {
    const int ent = dlist[e];
    const int it = ent >> 5, spl = ent & 31;
    const int k  = spl * 256 + threadIdx.x;
    unsigned long long pk =
        cand_pack(cb, sc, zg + (size_t)it * Dd, Ag[it], k);
    #pragma unroll
    for (int off = 16; off; off >>= 1) {
      const unsigned long long o = __shfl_xor(pk, off);
      if (o < pk) pk = o;
    }
    if ((threadIdx.x & 31) == 0) atomicMin(pbrow + it, pk);
  }
}

// overflow fallback: normally 0 iterations
__global__ void k_rescan_slow(const float* __restrict__ z, const float* __restrict__ cb,
                              const float* __restrict__ sc,
                              const int* __restrict__ rc, const int* __restrict__ slist,
                              int* __restrict__ idxf, float* __restrict__ outIdx) {
  __shared__ float zrow[Dd];
  __shared__ float Ash;
  __shared__ float sval[256];
  __shared__ int   sidx[256];
  const int tid = threadIdx.x;
  const int cnt = rc[2];
  for (int it = blockIdx.x; it < cnt; it += gridDim.x) {
    const int m = slist[it];
    const int b = m / Tt, t = m & (Tt - 1);
    __syncthreads();
    zrow[tid] = z[(size_t)b * Dd * Tt + (size_t)tid * Tt + t];
    __syncthreads();
    if (tid == 0) Ash = np_sumsq256(zrow);
    __syncthreads();
    const float A = Ash;
    float best = INFINITY; int bi = 0x7fffffff;
    for (int k = tid; k < Kk; k += 256) {
      const float* cr = cb + (size_t)k * Dd;
      double a0 = 0.0, a1 = 0.0, a2 = 0.0, a3 = 0.0;
      for (int d = 0; d < Dd; d += 4) {
        const float4 c4 = *(const float4*)(cr + d);
        a0 = fma((double)c4.x, (double)zrow[d+0], a0);
        a1 = fma((double)c4.y, (double)zrow[d+1], a1);
        a2 = fma((double)c4.z, (double)zrow[d+2], a2);
        a3 = fma((double)c4.w, (double)zrow[d+3], a3);
      }
      const float M  = (float)((a0 + a1) + (a2 + a3));
      const float t1 = __fsub_rn(A, __fmul_rn(2.0f, M));
      const float dq = __fadd_rn(t1, sc[k]);
      if (dq < best) { best = dq; bi = k; }
    }
    sval[tid] = best; sidx[tid] = bi;
    __syncthreads();
    for (int off = 128; off; off >>= 1) {
      if (tid < off) {
        if (sval[tid+off] < sval[tid] ||
            (sval[tid+off] == sval[tid] && sidx[tid+off] < sidx[tid])) {
          sval[tid] = sval[tid+off]; sidx[tid] = sidx[tid+off];
        }
      }
      __syncthreads();
    }
    if (tid == 0) { idxf[m] = sidx[0]; outIdx[m] = (float)sidx[0]; }
    __syncthreads();
  }
}

// ---------------------------------------------------------------------------
// fused gather + transpose + STE + loss + final index resolution:
// out[b][d][t] = z + (cb[idx] - z); idx = pbrow result for rescanned rows.
// ---------------------------------------------------------------------------
__global__ void k_out(const float* __restrict__ z, const float* __restrict__ cb,
                      const int* __restrict__ idxf, const int* __restrict__ posm,
                      const unsigned long long* __restrict__ pbrow,
                      float* __restrict__ outZ, float* __restrict__ outIdx,
                      double* __restrict__ loss_accum) {
  __shared__ float tile[64][65];          // [d][t]
  const int tid = threadIdx.x;
  const int bidx = blockIdx.x;            // 8 * 4 * 32 = 1024
  const int b  = bidx >> 7;
  const int dt = (bidx >> 5) & 3;
  const int tt = bidx & 31;
  const int d0 = dt * 64, t0 = tt * 64;
  {
    const int r = tid >> 2, seg = tid & 3;
    const int m = b * Tt + t0 + r;
    int idx = idxf[m];
    const int pos = posm[m];
    if (pos >= 0) {
      const unsigned long long pb = pbrow[pos];
      if (pb != ~0ull) {
        idx = (int)(unsigned)(pb & 0xFFFFFFFFull);
        if (seg == 0) outIdx[m] = (float)idx;
      }
    }
    const float* src = cb + (size_t)idx * Dd + d0 + seg * 16;
    #pragma unroll
    for (int q4 = 0; q4 < 4; ++q4) {
      const float4 v = *(const float4*)(src + q4 * 4);
      tile[seg * 16 + q4 * 4 + 0][r] = v.x;
      tile[seg * 16 + q4 * 4 + 1][r] = v.y;
      tile[seg * 16 + q4 * 4 + 2][r] = v.z;
      tile[seg * 16 + q4 * 4 + 3][r] = v.w;
    }
  }
  __syncthreads();
  const float* zbase = z + ((size_t)b * Dd + d0) * Tt + t0;
  float*       obase = outZ + ((size_t)b * Dd + d0) * Tt + t0;
  double ls = 0.0;
  #pragma unroll
  for (int p = 0; p < 4; ++p) {
    const int d  = p * 16 + (tid >> 4);
    const int t4 = (tid & 15) * 4;
    const float4 zv = *(const float4*)(zbase + (size_t)d * Tt + t4);
    const float q0 = tile[d][t4+0], q1 = tile[d][t4+1];
    const float q2 = tile[d][t4+2], q3 = tile[d][t4+3];
    const float r0 = q0 - zv.x, r1 = q1 - zv.y, r2 = q2 - zv.z, r3 = q3 - zv.w;
    float4 o;
    o.x = zv.x + r0; o.y = zv.y + r1; o.z = zv.z + r2; o.w = zv.w + r3;
    *(float4*)(obase + (size_t)d * Tt + t4) = o;
    ls += (double)r0*r0 + (double)r1*r1 + (double)r2*r2 + (double)r3*r3;
  }
  #pragma unroll
  for (int off = 32; off; off >>= 1) ls += __shfl_down(ls, off);
  if ((tid & 63) == 0) atomicAdd(loss_accum, ls);
}

__global__ void k_finalize(const double* __restrict__ loss_accum, float* __restrict__ outLoss) {
  const double mean = *loss_accum / (double)((size_t)Bz * Dd * Tt);
  *outLoss = (float)(mean + 0.1 * mean);
}

// ---------------------------------------------------------------------------
extern "C" void kernel_launch(void* const* d_in, const int* in_sizes, int n_in,
                              void* d_out, int out_size, void* d_ws, size_t ws_size,
                              hipStream_t stream) {
  (void)in_sizes; (void)n_in; (void)out_size; (void)ws_size;
  const float* z  = (const float*)d_in[0];   // (B, D, T) fp32
  const float* cb = (const float*)d_in[1];   // (K, D)    fp32

  float* outZ    = (float*)d_out;
  float* outIdx  = outZ + (size_t)Bz * Dd * Tt;
  float* outLoss = outIdx + Mm;

  char* w = (char*)d_ws;
  double*    loss_accum = (double*)w;    w += 16;
  int*       rc         = (int*)w;       w += 16;   // [0]=rows [1]=dumps [2]=slow
  int*       rlist      = (int*)w;       w += sizeof(int)   * Mm;
  int*       slist      = (int*)w;       w += sizeof(int)   * Mm;
  int*       idxf       = (int*)w;       w += sizeof(int)   * Mm;
  int*       posm       = (int*)w;       w += sizeof(int)   * Mm;
  float*     sc         = (float*)w;     w += sizeof(float) * Kk;
  float*     rthr       = (float*)w;     w += sizeof(float) * ZG_CAP;
  int*       dlist      = (int*)w;       w += sizeof(int)   * DUMP_CAP;
  _Float16*  Ah         = (_Float16*)w;  w += sizeof(_Float16) * (size_t)Mm * Dd;
  _Float16*  Bh         = (_Float16*)w;  w += sizeof(_Float16) * (size_t)Kk * Dd;
  float*     zg         = (float*)w;     w += sizeof(float) * (size_t)ZG_CAP * Dd;
  float*     Ag         = (float*)w;     w += sizeof(float) * ZG_CAP;
  unsigned long long* pbrow = (unsigned long long*)w; w += sizeof(unsigned long long) * ZG_CAP;
  float*     pd1        = (float*)w;     w += sizeof(float) * (size_t)NSPL * Mm;
  float*     pd2        = (float*)w;     w += sizeof(float) * (size_t)NSPL * Mm;
  int*       pi1        = (int*)w;       /* total ~24 MB */

  k_pre          <<<dim3(2304), 256, 0, stream>>>(z, cb, Ah, Bh, sc, loss_accum, rc);
  k_mfma         <<<dim3((Mm / 128) * (Kk / 256)), 512, 0, stream>>>(Ah, Bh, sc, pd1, pd2, pi1);
  k_combine      <<<dim3(Mm / 64), 64, 0, stream>>>(pd1, pd2, pi1, idxf, rc, rlist, rthr, posm, slist, pbrow, outIdx);
  k_rescan_rows  <<<dim3(ZG_CAP / 4), 256, 0, stream>>>(z, cb, sc, rc, rlist, rthr, pd1, pd2, pi1, zg, Ag, dlist, pbrow);
  k_rescan_dumps <<<dim3(256), 256, 0, stream>>>(cb, sc, rc, dlist, zg, Ag, pbrow);
  k_rescan_slow  <<<dim3(64), 256, 0, stream>>>(z, cb, sc, rc, slist, idxf, outIdx);
  k_out          <<<dim3(1024), 256, 0, stream>>>(z, cb, idxf, posm, pbrow, outZ, outIdx, loss_accum);
  k_finalize     <<<dim3(1), 1, 0, stream>>>(loss_accum, outLoss);
}